// Round 8
// baseline (193.219 us; speedup 1.0000x reference)
//
#include <hip/hip_runtime.h>
#include <math.h>

// Problem constants (from reference)
#define BB 16
#define VV 6890
#define NFF 13776
#define HH 512
#define WW 512
#define CAP 32            // fallback path: vertex-degree bucket capacity
// SIGMA = 1e-4 -> 1/SIGMA = 1e4

#define NS 16                 // face-slices per batch; grid = BB*NS = 256 blocks
#define FPS (NFF / NS)        // 861 faces per slice (exact: 861*16 = 13776)
#define MT 1024               // threads per mesh block

typedef float nf4 __attribute__((ext_vector_type(4)));

// ---------------------------------------------------------------------------
// PRIMARY D2 (k_mesh): ONE dispatch for the entire mesh pipeline.
//   Phase A (256 blocks): block (b,s) computes its 861 face normals inline,
//     scatter-adds into an 82.7KB private LDS accumulator, writes the
//     partial out coalesced.
//   Fan-in: store-drain at __syncthreads, then release __threadfence +
//     atomicAdd(done[b]). Exactly one last-arriver block per batch proceeds
//     (no co-residency assumption, no spin, no grid sync).
//   Phase B (16 tail blocks): reduce the 16 partials (coalesced), normalize
//     into the now-free LDS, then fas[b,f] = vn[i0]+vn[i1]+vn[i2] from LDS.
// ---------------------------------------------------------------------------
__global__ __launch_bounds__(MT) void k_mesh(const float* __restrict__ verts,
                                             const int* __restrict__ faces,
                                             float* __restrict__ partial,
                                             float4* __restrict__ fas4,
                                             int* __restrict__ done) {
    __shared__ float vx[VV];
    __shared__ float vy[VV];
    __shared__ float vz[VV];
    __shared__ int is_last;
    const int b = blockIdx.x / NS;
    const int s = blockIdx.x - b * NS;
    const int t = threadIdx.x;

    // ---- Phase A: slice scatter into LDS ----
    for (int v = t; v < VV; v += MT) { vx[v] = 0.f; vy[v] = 0.f; vz[v] = 0.f; }
    __syncthreads();

    const float* vb = verts + (size_t)b * (VV * 3);
    if (t < FPS) {                       // one face per thread (861 < 1024)
        int f = s * FPS + t;
        int i0 = faces[3 * f + 0];
        int i1 = faces[3 * f + 1];
        int i2 = faces[3 * f + 2];
        float ax = vb[3 * i0 + 0], ay = vb[3 * i0 + 1], az = vb[3 * i0 + 2];
        float bx = vb[3 * i1 + 0], by = vb[3 * i1 + 1], bz = vb[3 * i1 + 2];
        float cx = vb[3 * i2 + 0], cy = vb[3 * i2 + 1], cz = vb[3 * i2 + 2];
        float e1x = bx - ax, e1y = by - ay, e1z = bz - az;
        float e2x = cx - ax, e2y = cy - ay, e2z = cz - az;
        float nx = e1y * e2z - e1z * e2y;
        float ny = e1z * e2x - e1x * e2z;
        float nz = e1x * e2y - e1y * e2x;
        atomicAdd(&vx[i0], nx); atomicAdd(&vy[i0], ny); atomicAdd(&vz[i0], nz);
        atomicAdd(&vx[i1], nx); atomicAdd(&vy[i1], ny); atomicAdd(&vz[i1], nz);
        atomicAdd(&vx[i2], nx); atomicAdd(&vy[i2], ny); atomicAdd(&vz[i2], nz);
    }
    __syncthreads();

    float* pb = partial + (size_t)blockIdx.x * (3 * VV);
    for (int v = t; v < VV; v += MT) pb[v] = vx[v];
    for (int v = t; v < VV; v += MT) pb[VV + v] = vy[v];
    for (int v = t; v < VV; v += MT) pb[2 * VV + v] = vz[v];
    __syncthreads();   // compiler drains vmcnt(0) before s_barrier: all stores complete

    // ---- Fan-in: last arriver per batch ----
    if (t == 0) {
        __threadfence();                       // release: partials device-visible
        int old = atomicAdd(&done[b], 1);
        is_last = (old == NS - 1) ? 1 : 0;
    }
    __syncthreads();
    if (!is_last) return;
    __threadfence();                           // acquire: drop stale cached lines

    // ---- Phase B: reduce 16 partials -> vn in LDS, then fas for batch b ----
    const float* pbase = partial + (size_t)b * NS * (3 * VV);
    for (int v = t; v < VV; v += MT) {
        float x = 0.f, y = 0.f, z = 0.f;
#pragma unroll
        for (int ss = 0; ss < NS; ss++) {
            const float* ps = pbase + (size_t)ss * (3 * VV);
            x += ps[v];
            y += ps[VV + v];
            z += ps[2 * VV + v];
        }
        float inv = 1.0f / fmaxf(sqrtf(x * x + y * y + z * z), 1e-6f);
        vx[v] = x * inv; vy[v] = y * inv; vz[v] = z * inv;
    }
    __syncthreads();

    float4* fasb = fas4 + (size_t)b * NFF;
    for (int f = t; f < NFF; f += MT) {
        int i0 = faces[3 * f + 0];
        int i1 = faces[3 * f + 1];
        int i2 = faces[3 * f + 2];
        float4 o;
        o.x = vx[i0] + vx[i1] + vx[i2];
        o.y = vy[i0] + vy[i1] + vy[i2];
        o.z = vz[i0] + vz[i1] + vz[i2];
        o.w = 0.f;
        fasb[f] = o;
    }
}

// ---------------------------------------------------------------------------
// k_pixel: byte-for-byte proven round-6 code (41.8us, ideal traffic: FETCH =
// p2f+dists, gathers 100% L2-hit, WRITE = output exactly). STRIDED 8
// px/thread; 8 independent clamped gathers in flight.
// ---------------------------------------------------------------------------
__device__ __forceinline__ nf4 pixel_one(int f, float d, float4 p) {
    float m = (f >= 0) ? 1.0f : 0.0f;
    float px = p.x * m, py = p.y * m, pz = p.z * m;
    float prob = m / (1.0f + __expf(d * 1.0e4f));  // sigmoid(-d/SIGMA) * mask
    float n2 = px * px + py * py + pz * pz;
    float inv = 1.0f / fmaxf(sqrtf(n2), 1e-12f);
    float hitadd = (n2 > 0.f) ? 0.f : 1.0f;
    nf4 o;
    o.x = px * inv + hitadd;
    o.y = py * inv + hitadd;
    o.z = pz * inv + hitadd;
    o.w = 1.0f - prob;
    return o;
}

#define PPT 8
#define PIX_BLOCK (256 * PPT)  // 2048 pixels/block; 2048 blocks; 128 blocks/batch

__global__ __launch_bounds__(256) void k_pixel(const int* __restrict__ p2f,
                                               const float* __restrict__ dists,
                                               const float4* __restrict__ fas4,
                                               nf4* __restrict__ out) {
    int base = blockIdx.x * PIX_BLOCK;
    int t = threadIdx.x;
    int b = base >> 18;  // H*W = 2^18; a 2048-pixel block never crosses a batch
    const float4* fasb = fas4 + (size_t)b * NFF;

    int   f[PPT];
    float d[PPT];
    float4 p[PPT];

#pragma unroll
    for (int k = 0; k < PPT; k++)
        f[k] = __builtin_nontemporal_load(p2f + base + k * 256 + t);
#pragma unroll
    for (int k = 0; k < PPT; k++)
        d[k] = __builtin_nontemporal_load(dists + base + k * 256 + t);

#pragma unroll
    for (int k = 0; k < PPT; k++)
        p[k] = fasb[min(max(f[k], 0), NFF - 1)];

#pragma unroll
    for (int k = 0; k < PPT; k++) {
        nf4 o = pixel_one(f[k], d[k], p[k]);
        __builtin_nontemporal_store(o, out + base + k * 256 + t);
    }
}

// ---------------------------------------------------------------------------
// FALLBACK: byte-for-byte round-4 CSR pipeline (proven 159.7us, ~9.7MB ws).
// ---------------------------------------------------------------------------
__global__ __launch_bounds__(256) void k_fn_adj(const float* __restrict__ verts,
                                                const int* __restrict__ faces,
                                                float4* __restrict__ fn4,
                                                int* __restrict__ cursor,
                                                int* __restrict__ adj) {
    if (blockIdx.x < 861) {
        int i = blockIdx.x * 256 + threadIdx.x;
        int b = i / NFF;
        int f = i - b * NFF;
        int i0 = faces[3 * f + 0];
        int i1 = faces[3 * f + 1];
        int i2 = faces[3 * f + 2];
        const float* vb = verts + (size_t)b * (VV * 3);
        float ax = vb[3 * i0 + 0], ay = vb[3 * i0 + 1], az = vb[3 * i0 + 2];
        float bx = vb[3 * i1 + 0], by = vb[3 * i1 + 1], bz = vb[3 * i1 + 2];
        float cx = vb[3 * i2 + 0], cy = vb[3 * i2 + 1], cz = vb[3 * i2 + 2];
        float e1x = bx - ax, e1y = by - ay, e1z = bz - az;
        float e2x = cx - ax, e2y = cy - ay, e2z = cz - az;
        float4 n;
        n.x = e1y * e2z - e1z * e2y;
        n.y = e1z * e2x - e1x * e2z;
        n.z = e1x * e2y - e1y * e2x;
        n.w = 0.f;
        fn4[i] = n;
    } else {
        int f = (blockIdx.x - 861) * 256 + threadIdx.x;
        if (f < NFF) {
            int i0 = faces[3 * f + 0];
            int i1 = faces[3 * f + 1];
            int i2 = faces[3 * f + 2];
            int s0 = atomicAdd(&cursor[i0], 1);
            if (s0 < CAP) adj[s0 * VV + i0] = f;
            int s1 = atomicAdd(&cursor[i1], 1);
            if (s1 < CAP) adj[s1 * VV + i1] = f;
            int s2 = atomicAdd(&cursor[i2], 1);
            if (s2 < CAP) adj[s2 * VV + i2] = f;
        }
    }
}

__global__ __launch_bounds__(256) void k_vn(const float4* __restrict__ fn4,
                                            const int* __restrict__ cursor,
                                            const int* __restrict__ adj,
                                            float4* __restrict__ vn4) {
    int i = blockIdx.x * 256 + threadIdx.x;
    if (i >= BB * VV) return;
    int b = i / VV;
    int v = i - b * VV;
    int deg = min(cursor[v], CAP);
    float x = 0.f, y = 0.f, z = 0.f;
    const float4* fnb = fn4 + (size_t)b * NFF;
    for (int j = 0; j < deg; j++) {
        float4 n = fnb[adj[j * VV + v]];
        x += n.x; y += n.y; z += n.z;
    }
    float inv = 1.0f / fmaxf(sqrtf(x * x + y * y + z * z), 1e-6f);
    float4 o; o.x = x * inv; o.y = y * inv; o.z = z * inv; o.w = 0.f;
    vn4[i] = o;
}

__global__ __launch_bounds__(256) void k_fas(const float4* __restrict__ vn4,
                                             const int* __restrict__ faces,
                                             float4* __restrict__ fas4) {
    int i = blockIdx.x * 256 + threadIdx.x;   // exact: 861*256 == BB*NFF
    int b = i / NFF;
    int f = i - b * NFF;
    int i0 = faces[3 * f + 0], i1 = faces[3 * f + 1], i2 = faces[3 * f + 2];
    const float4* vnb = vn4 + (size_t)b * VV;
    float4 a = vnb[i0], bb = vnb[i1], cc = vnb[i2];
    float4 o;
    o.x = a.x + bb.x + cc.x;
    o.y = a.y + bb.y + cc.y;
    o.z = a.z + bb.z + cc.z;
    o.w = 0.f;
    fas4[i] = o;
}

// ---------------------------------------------------------------------------
extern "C" void kernel_launch(void* const* d_in, const int* in_sizes, int n_in,
                              void* d_out, int out_size, void* d_ws, size_t ws_size,
                              hipStream_t stream) {
    const float* verts = (const float*)d_in[0];
    // d_in[1] = zbuf: dead in the reference's returned value -> never read
    const float* dists = (const float*)d_in[2];
    const int* faces   = (const int*)d_in[3];
    const int* p2f     = (const int*)d_in[4];

    const size_t partial_bytes = (size_t)BB * NS * 3 * VV * sizeof(float);  // 21.17 MB
    const size_t fas_bytes     = (size_t)BB * NFF * 16;                     // 3.53 MB
    const size_t need_primary  = partial_bytes + fas_bytes + 256;

    if (ws_size >= need_primary) {
        // --- primary: single-dispatch mesh pipeline (fan-in), then pixel ---
        char* w = (char*)d_ws;
        float* partial = (float*)w;  w += partial_bytes;
        float4* fas4   = (float4*)w; w += fas_bytes;
        int* done      = (int*)w;

        (void)hipMemsetAsync(done, 0, BB * sizeof(int), stream);
        k_mesh<<<BB * NS, MT, 0, stream>>>(verts, faces, partial, fas4, done);
        k_pixel<<<BB * HH * WW / PIX_BLOCK, 256, 0, stream>>>(p2f, dists, fas4, (nf4*)d_out);
    } else {
        // --- fallback: proven round-4 CSR pipeline (~9.7MB) ---
        char* w = (char*)d_ws;
        float4* fn4  = (float4*)w;  w += (size_t)BB * NFF * 16;
        float4* vn4  = (float4*)w;  w += (size_t)BB * VV * 16;
        float4* fas4 = (float4*)w;  w += fas_bytes;
        int* cursor  = (int*)w;     w += (VV * 4 + 15) / 16 * 16;
        int* adj     = (int*)w;

        (void)hipMemsetAsync(cursor, 0, VV * sizeof(int), stream);
        k_fn_adj<<<861 + (NFF + 255) / 256, 256, 0, stream>>>(verts, faces, fn4, cursor, adj);
        k_vn<<<(BB * VV + 255) / 256, 256, 0, stream>>>(fn4, cursor, adj, vn4);
        k_fas<<<861, 256, 0, stream>>>(vn4, faces, fas4);
        k_pixel<<<BB * HH * WW / PIX_BLOCK, 256, 0, stream>>>(p2f, dists, fas4, (nf4*)d_out);
    }
}

// Round 9
// 153.371 us; speedup vs baseline: 1.2598x; 1.2598x over previous
//
#include <hip/hip_runtime.h>
#include <math.h>

// Problem constants (from reference)
#define BB 16
#define VV 6890
#define NFF 13776
#define HH 512
#define WW 512
#define CAP 32            // fallback path: vertex-degree bucket capacity
// SIGMA = 1e-4 -> 1/SIGMA = 1e4

#define NS 16             // face-slices per batch; grid = BB*NS = 256 blocks (1/CU)
#define FPS (NFF / NS)    // 861 faces per slice (exact: 861*16 = 13776)

typedef float nf4 __attribute__((ext_vector_type(4)));

// ---------------------------------------------------------------------------
// D1 (k_scatter): proven round-6 code. Block (b,s) computes face normals for
// its 861-face slice inline and scatter-adds into a private 82.7KB LDS
// accumulator; 256 blocks = 1/CU, ~7.7K LDS atomics each. Partial written
// coalesced. (Round-8 proved fusing the reduce into a 16-block tail is WORSE:
// 16-CU starvation + cross-XCD partial reads.)
// ---------------------------------------------------------------------------
__global__ __launch_bounds__(512) void k_scatter(const float* __restrict__ verts,
                                                 const int* __restrict__ faces,
                                                 float* __restrict__ partial) {
    __shared__ float vx[VV];
    __shared__ float vy[VV];
    __shared__ float vz[VV];
    const int b = blockIdx.x / NS;
    const int s = blockIdx.x - b * NS;
    const int t = threadIdx.x;

    for (int v = t; v < VV; v += 512) { vx[v] = 0.f; vy[v] = 0.f; vz[v] = 0.f; }
    __syncthreads();

    const float* vb = verts + (size_t)b * (VV * 3);
    const int fend = (s + 1) * FPS;
    for (int f = s * FPS + t; f < fend; f += 512) {
        int i0 = faces[3 * f + 0];
        int i1 = faces[3 * f + 1];
        int i2 = faces[3 * f + 2];
        float ax = vb[3 * i0 + 0], ay = vb[3 * i0 + 1], az = vb[3 * i0 + 2];
        float bx = vb[3 * i1 + 0], by = vb[3 * i1 + 1], bz = vb[3 * i1 + 2];
        float cx = vb[3 * i2 + 0], cy = vb[3 * i2 + 1], cz = vb[3 * i2 + 2];
        float e1x = bx - ax, e1y = by - ay, e1z = bz - az;
        float e2x = cx - ax, e2y = cy - ay, e2z = cz - az;
        float nx = e1y * e2z - e1z * e2y;
        float ny = e1z * e2x - e1x * e2z;
        float nz = e1x * e2y - e1y * e2x;
        atomicAdd(&vx[i0], nx); atomicAdd(&vy[i0], ny); atomicAdd(&vz[i0], nz);
        atomicAdd(&vx[i1], nx); atomicAdd(&vy[i1], ny); atomicAdd(&vz[i1], nz);
        atomicAdd(&vx[i2], nx); atomicAdd(&vy[i2], ny); atomicAdd(&vz[i2], nz);
    }
    __syncthreads();

    float* pb = partial + (size_t)blockIdx.x * (3 * VV);
    for (int v = t; v < VV; v += 512) pb[v] = vx[v];
    for (int v = t; v < VV; v += 512) pb[VV + v] = vy[v];
    for (int v = t; v < VV; v += 512) pb[2 * VV + v] = vz[v];
}

// ---------------------------------------------------------------------------
// D2 (k_vred): proven round-6 code. vn[b,v] = normalize(sum of 16 partials);
// 48 coalesced independent loads per thread.
// ---------------------------------------------------------------------------
__global__ __launch_bounds__(256) void k_vred(const float* __restrict__ partial,
                                              float4* __restrict__ vn4) {
    int i = blockIdx.x * 256 + threadIdx.x;
    if (i >= BB * VV) return;
    int b = i / VV;
    int v = i - b * VV;
    float x = 0.f, y = 0.f, z = 0.f;
    const float* pb = partial + (size_t)b * NS * (3 * VV);
#pragma unroll
    for (int s = 0; s < NS; s++) {
        const float* ps = pb + (size_t)s * (3 * VV);
        x += ps[v];
        y += ps[VV + v];
        z += ps[2 * VV + v];
    }
    float inv = 1.0f / fmaxf(sqrtf(x * x + y * y + z * z), 1e-6f);
    float4 o; o.x = x * inv; o.y = y * inv; o.z = z * inv; o.w = 0.f;
    vn4[i] = o;
}

// ---------------------------------------------------------------------------
// D3 (k_fas): NOW PRE-NORMALIZES. fasn[b,f] = normalize(vn[i0]+vn[i1]+vn[i2]).
// The per-pixel normalize depends only on the face -> do it here (220K faces)
// instead of in k_pixel (4.2M pixels, 19x more). Zero-sum stays zero (0*1e12).
// ---------------------------------------------------------------------------
__global__ __launch_bounds__(256) void k_fas(const float4* __restrict__ vn4,
                                             const int* __restrict__ faces,
                                             float4* __restrict__ fasn4) {
    int i = blockIdx.x * 256 + threadIdx.x;   // exact: 861*256 == BB*NFF
    int b = i / NFF;
    int f = i - b * NFF;
    int i0 = faces[3 * f + 0], i1 = faces[3 * f + 1], i2 = faces[3 * f + 2];
    const float4* vnb = vn4 + (size_t)b * VV;
    float4 a = vnb[i0], bb = vnb[i1], cc = vnb[i2];
    float x = a.x + bb.x + cc.x;
    float y = a.y + bb.y + cc.y;
    float z = a.z + bb.z + cc.z;
    float inv = 1.0f / fmaxf(sqrtf(x * x + y * y + z * z), 1e-12f);
    float4 o; o.x = x * inv; o.y = y * inv; o.z = z * inv; o.w = 0.f;
    fasn4[i] = o;
}

// ---------------------------------------------------------------------------
// D4 (k_pixel): strided 8 px/thread (proven layout). CHANGES vs round 6:
//  - REGULAR stores (not nontemporal): nt stores bypass L2 and force the
//    67MB write stream synchronously to HBM; cached stores let the 32MB L2
//    absorb bursts and write back overlapped with the read stream. (Theory
//    for the 42us vs 16us-roofline gap.)
//  - fasn is pre-normalized: per-pixel work is mask+sigmoid only.
//  - clamp is max(f,0) only (p2f < NFF by construction).
// ---------------------------------------------------------------------------
__device__ __forceinline__ nf4 pixel_one(int f, float d, float4 p) {
    float m = (f >= 0) ? 1.0f : 0.0f;
    float px = p.x * m, py = p.y * m, pz = p.z * m;
    float prob = m / (1.0f + __expf(d * 1.0e4f));  // sigmoid(-d/SIGMA) * mask
    float n2 = px * px + py * py + pz * pz;
    float hitadd = (n2 > 0.f) ? 0.f : 1.0f;
    nf4 o;
    o.x = px + hitadd;
    o.y = py + hitadd;
    o.z = pz + hitadd;
    o.w = 1.0f - prob;
    return o;
}

#define PPT 8
#define PIX_BLOCK (256 * PPT)  // 2048 pixels/block; 2048 blocks; 128 blocks/batch

__global__ __launch_bounds__(256) void k_pixel(const int* __restrict__ p2f,
                                               const float* __restrict__ dists,
                                               const float4* __restrict__ fasn4,
                                               nf4* __restrict__ out) {
    int base = blockIdx.x * PIX_BLOCK;
    int t = threadIdx.x;
    int b = base >> 18;  // H*W = 2^18; a 2048-pixel block never crosses a batch
    const float4* fasb = fasn4 + (size_t)b * NFF;

    int   f[PPT];
    float d[PPT];
    float4 p[PPT];

#pragma unroll
    for (int k = 0; k < PPT; k++)
        f[k] = __builtin_nontemporal_load(p2f + base + k * 256 + t);
#pragma unroll
    for (int k = 0; k < PPT; k++)
        d[k] = __builtin_nontemporal_load(dists + base + k * 256 + t);

#pragma unroll
    for (int k = 0; k < PPT; k++)
        p[k] = fasb[max(f[k], 0)];

#pragma unroll
    for (int k = 0; k < PPT; k++) {
        nf4 o = pixel_one(f[k], d[k], p[k]);
        out[base + k * 256 + t] = o;   // regular store: L2 write-back path
    }
}

// ---------------------------------------------------------------------------
// FALLBACK (ws too small; never expected -- ws measured ~268MB via poison
// fill): round-4 CSR pipeline, proven 159.7us, ~9.7MB.
// ---------------------------------------------------------------------------
__global__ __launch_bounds__(256) void k_fn_adj(const float* __restrict__ verts,
                                                const int* __restrict__ faces,
                                                float4* __restrict__ fn4,
                                                int* __restrict__ cursor,
                                                int* __restrict__ adj) {
    if (blockIdx.x < 861) {
        int i = blockIdx.x * 256 + threadIdx.x;
        int b = i / NFF;
        int f = i - b * NFF;
        int i0 = faces[3 * f + 0];
        int i1 = faces[3 * f + 1];
        int i2 = faces[3 * f + 2];
        const float* vb = verts + (size_t)b * (VV * 3);
        float ax = vb[3 * i0 + 0], ay = vb[3 * i0 + 1], az = vb[3 * i0 + 2];
        float bx = vb[3 * i1 + 0], by = vb[3 * i1 + 1], bz = vb[3 * i1 + 2];
        float cx = vb[3 * i2 + 0], cy = vb[3 * i2 + 1], cz = vb[3 * i2 + 2];
        float e1x = bx - ax, e1y = by - ay, e1z = bz - az;
        float e2x = cx - ax, e2y = cy - ay, e2z = cz - az;
        float4 n;
        n.x = e1y * e2z - e1z * e2y;
        n.y = e1z * e2x - e1x * e2z;
        n.z = e1x * e2y - e1y * e2x;
        n.w = 0.f;
        fn4[i] = n;
    } else {
        int f = (blockIdx.x - 861) * 256 + threadIdx.x;
        if (f < NFF) {
            int i0 = faces[3 * f + 0];
            int i1 = faces[3 * f + 1];
            int i2 = faces[3 * f + 2];
            int s0 = atomicAdd(&cursor[i0], 1);
            if (s0 < CAP) adj[s0 * VV + i0] = f;
            int s1 = atomicAdd(&cursor[i1], 1);
            if (s1 < CAP) adj[s1 * VV + i1] = f;
            int s2 = atomicAdd(&cursor[i2], 1);
            if (s2 < CAP) adj[s2 * VV + i2] = f;
        }
    }
}

__global__ __launch_bounds__(256) void k_vn(const float4* __restrict__ fn4,
                                            const int* __restrict__ cursor,
                                            const int* __restrict__ adj,
                                            float4* __restrict__ vn4) {
    int i = blockIdx.x * 256 + threadIdx.x;
    if (i >= BB * VV) return;
    int b = i / VV;
    int v = i - b * VV;
    int deg = min(cursor[v], CAP);
    float x = 0.f, y = 0.f, z = 0.f;
    const float4* fnb = fn4 + (size_t)b * NFF;
    for (int j = 0; j < deg; j++) {
        float4 n = fnb[adj[j * VV + v]];
        x += n.x; y += n.y; z += n.z;
    }
    float inv = 1.0f / fmaxf(sqrtf(x * x + y * y + z * z), 1e-6f);
    float4 o; o.x = x * inv; o.y = y * inv; o.z = z * inv; o.w = 0.f;
    vn4[i] = o;
}

// ---------------------------------------------------------------------------
extern "C" void kernel_launch(void* const* d_in, const int* in_sizes, int n_in,
                              void* d_out, int out_size, void* d_ws, size_t ws_size,
                              hipStream_t stream) {
    const float* verts = (const float*)d_in[0];
    // d_in[1] = zbuf: dead in the reference's returned value -> never read
    const float* dists = (const float*)d_in[2];
    const int* faces   = (const int*)d_in[3];
    const int* p2f     = (const int*)d_in[4];

    const size_t partial_bytes = (size_t)BB * NS * 3 * VV * sizeof(float);  // 21.17 MB
    const size_t vn_bytes      = (size_t)BB * VV * 16;                      // 1.76 MB
    const size_t fas_bytes     = (size_t)BB * NFF * 16;                     // 3.53 MB

    int nbv = BB * VV;   // 110240

    if (ws_size >= partial_bytes + vn_bytes + fas_bytes) {
        // --- primary: round-6 proven structure + round-9 kernel tweaks ---
        char* w = (char*)d_ws;
        float* partial = (float*)w;  w += partial_bytes;
        float4* vn4    = (float4*)w; w += vn_bytes;
        float4* fasn4  = (float4*)w;

        k_scatter<<<BB * NS, 512, 0, stream>>>(verts, faces, partial);
        k_vred<<<(nbv + 255) / 256, 256, 0, stream>>>(partial, vn4);
        k_fas<<<861, 256, 0, stream>>>(vn4, faces, fasn4);
        k_pixel<<<BB * HH * WW / PIX_BLOCK, 256, 0, stream>>>(p2f, dists, fasn4, (nf4*)d_out);
    } else {
        // --- fallback: round-4 CSR pipeline ---
        char* w = (char*)d_ws;
        float4* fn4  = (float4*)w;  w += (size_t)BB * NFF * 16;
        float4* vn4  = (float4*)w;  w += vn_bytes;
        float4* fasn4 = (float4*)w; w += fas_bytes;
        int* cursor  = (int*)w;     w += (VV * 4 + 15) / 16 * 16;
        int* adj     = (int*)w;

        (void)hipMemsetAsync(cursor, 0, VV * sizeof(int), stream);
        k_fn_adj<<<861 + (NFF + 255) / 256, 256, 0, stream>>>(verts, faces, fn4, cursor, adj);
        k_vn<<<(nbv + 255) / 256, 256, 0, stream>>>(fn4, cursor, adj, vn4);
        k_fas<<<861, 256, 0, stream>>>(vn4, faces, fasn4);
        k_pixel<<<BB * HH * WW / PIX_BLOCK, 256, 0, stream>>>(p2f, dists, fasn4, (nf4*)d_out);
    }
}